// Round 8
// baseline (837.751 us; speedup 1.0000x reference)
//
#include <hip/hip_runtime.h>

#define IN_DIM 128
#define OUT_DIM 64
#define PADF 36     // gemm LDS row stride in floats
#define BK_BITS 6   // 64-node buckets
#define BK_NODES 64
#define CPAD 16     // cursor/count padding: one int per 64B line

static inline size_t align_up(size_t v, size_t a) { return (v + a - 1) & ~(a - 1); }

// ---------- GEMM: h = x @ W ----------
// 256 threads = 4 waves; wave wv computes cols [16wv,16wv+16), lane = row.
// W loads wave-uniform -> s_load; acc[16] static -> VGPRs. (r6: left top-5)
__global__ __launch_bounds__(256, 8) void gemm_block(
    const float* __restrict__ x, const float* __restrict__ w,
    float* __restrict__ h, int nrows) {
  __shared__ float xt[64 * PADF];
  const int tid = threadIdx.x;
  const int lane = tid & 63;
  const int wv = __builtin_amdgcn_readfirstlane(tid >> 6);  // 0..3, SGPR
  const int rb = blockIdx.x * 64;

  float acc[16];
#pragma unroll
  for (int c = 0; c < 16; ++c) acc[c] = 0.f;

  const int r = tid >> 3;
  const int kq = (tid & 7) << 2;
  const float* wbase = w + wv * 16;

#pragma unroll 1
  for (int kc = 0; kc < IN_DIM; kc += 32) {
#pragma unroll
    for (int p = 0; p < 2; ++p) {
      int row = rb + r + p * 32;
      float4 v = (row < nrows)
                     ? *reinterpret_cast<const float4*>(x + (size_t)row * IN_DIM + kc + kq)
                     : make_float4(0.f, 0.f, 0.f, 0.f);
      *reinterpret_cast<float4*>(&xt[(r + p * 32) * PADF + kq]) = v;
    }
    __syncthreads();
#pragma unroll
    for (int k4 = 0; k4 < 32; k4 += 4) {
      float4 xv = *reinterpret_cast<const float4*>(&xt[lane * PADF + k4]);
#pragma unroll
      for (int kk = 0; kk < 4; ++kk) {
        float xs = (&xv.x)[kk];
        const float* wk = wbase + (size_t)(kc + k4 + kk) * OUT_DIM;  // uniform -> s_load
#pragma unroll
        for (int c = 0; c < 16; ++c)
          acc[c] = fmaf(xs, wk[c], acc[c]);
      }
    }
    __syncthreads();
  }

  int row = rb + lane;
  if (row < nrows) {
    float4* hp = reinterpret_cast<float4*>(h + (size_t)row * OUT_DIM + wv * 16);
#pragma unroll
    for (int c4 = 0; c4 < 4; ++c4)
      hp[c4] = make_float4(acc[c4 * 4], acc[c4 * 4 + 1], acc[c4 * 4 + 2], acc[c4 * 4 + 3]);
  }
}

// ---------- bucket CSR build ----------

__global__ __launch_bounds__(256) void zero_i32(int* __restrict__ p, int n) {
  int tid = blockIdx.x * blockDim.x + threadIdx.x;
  int stride = gridDim.x * blockDim.x;
  for (int i = tid; i < n; i += stride) p[i] = 0;
}

// Bucket histogram via per-block LDS: one 6.4 MB dst read (vs 51.2 MB
// partitioned per-dst hist), flush = nblocks*nb global atomics on padded
// counters.
__global__ __launch_bounds__(256) void hist_lds_kernel(
    const int* __restrict__ dst, int nedges, int* __restrict__ counts_pad,
    int nb) {
  __shared__ int hcnt[2048];
  const int tid = threadIdx.x;
  for (int i = tid; i < nb; i += 256) hcnt[i] = 0;
  __syncthreads();
  int gid = blockIdx.x * blockDim.x + tid;
  int stride = gridDim.x * blockDim.x;
  for (int e = gid; e < nedges; e += stride) {
    int d = __builtin_nontemporal_load(dst + e);
    atomicAdd(&hcnt[d >> BK_BITS], 1);
  }
  __syncthreads();
  for (int i = tid; i < nb; i += 256) {
    int v = hcnt[i];
    if (v) atomicAdd(&counts_pad[i * CPAD], v);
  }
}

// Single-block exclusive scan of nb (<=2047) bucket counts (2 elems/thread,
// Hillis-Steele, double-buffered). Writes offsets[0..nb] and seeds cursors.
__global__ __launch_bounds__(1024) void scan_buckets_kernel(
    const int* __restrict__ counts_pad, int nb, int* __restrict__ offsets,
    int* __restrict__ cursor_pad) {
  __shared__ int sb[2][2048];
  const int tid = threadIdx.x;
  const int i0 = tid * 2, i1 = tid * 2 + 1;
  sb[0][i0] = (i0 < nb) ? counts_pad[i0 * CPAD] : 0;
  sb[0][i1] = (i1 < nb) ? counts_pad[i1 * CPAD] : 0;
  __syncthreads();
  int cur = 0;
  for (int d = 1; d < 2048; d <<= 1) {
    int a0 = sb[cur][i0] + ((i0 >= d) ? sb[cur][i0 - d] : 0);
    int a1 = sb[cur][i1] + ((i1 >= d) ? sb[cur][i1 - d] : 0);
    sb[cur ^ 1][i0] = a0;
    sb[cur ^ 1][i1] = a1;
    cur ^= 1;
    __syncthreads();
  }
  // sb[cur][i] = inclusive sum
  if (i0 <= nb) {
    int e0 = (i0 == 0) ? 0 : sb[cur][i0 - 1];
    offsets[i0] = e0;
    if (i0 < nb) cursor_pad[i0 * CPAD] = e0;
  }
  if (i1 <= nb) {
    int e1 = sb[cur][i1 - 1];
    offsets[i1] = e1;
    if (i1 < nb) cursor_pad[i1 * CPAD] = e1;
  }
}

// XCD-range-partitioned bucket fill. Append-only per bucket: active write
// tails = ~195 lines/XCD (12.5 KB, vs per-dst fill's 800 KB) -> L2
// write-combines. Padded cursors: no same-line atomic serialization.
__global__ __launch_bounds__(256) void bucket_fill_kernel(
    const int* __restrict__ ei, const float* __restrict__ ew, int nedges,
    int* __restrict__ cursor_pad, int2* __restrict__ bucketed, int nb) {
  const int range = blockIdx.x & 7;
  const int ngroups = gridDim.x >> 3;
  const int group = blockIdx.x >> 3;
  const int lo = (int)((size_t)range * nb / 8);
  const int hi = (int)((size_t)(range + 1) * nb / 8);
  int tid = group * blockDim.x + threadIdx.x;
  int stride = ngroups * blockDim.x;
  for (int e = tid; e < nedges; e += stride) {
    int d = __builtin_nontemporal_load(ei + e);
    int b = d >> BK_BITS;
    if (b >= lo && b < hi) {
      int s = ei[nedges + e];
      float wv = ew[e];
      int p = atomicAdd(&cursor_pad[b * CPAD], 1);
      bucketed[p] = make_int2(s | ((d & (BK_NODES - 1)) << 20),
                              __float_as_int(wv));
    }
  }
}

// ---------- LDS-gather: one block per bucket ----------
// 16 KB fp32 tile [64 nodes][64 ch]; waves stream bucket edges, read h[src]
// coalesced (256B, L3-resident), ds_add_f32 into tile (2 lanes/bank = free).
// One clean 16 KB writeout with bias fused. No per-dst CSR, no shfl.
__global__ __launch_bounds__(256) void lds_gather_kernel(
    const int* __restrict__ offsets, const int2* __restrict__ bucketed,
    const float* __restrict__ h, const float* __restrict__ bias,
    float* __restrict__ out, int nnodes) {
  __shared__ float tile[BK_NODES * OUT_DIM];  // 16 KB
  const int tid = threadIdx.x;
  const int lane = tid & 63;
  const int wv = __builtin_amdgcn_readfirstlane(tid >> 6);
  const int b = blockIdx.x;

#pragma unroll
  for (int i = 0; i < BK_NODES * OUT_DIM / 256; ++i)
    tile[tid + i * 256] = 0.f;
  __syncthreads();

  const int beg = offsets[b];
  const int end = offsets[b + 1];
  const int cnt = end - beg;
  const int per = (cnt + 3) >> 2;
  int e = beg + wv * per;
  const int wend = min(e + per, end);

  for (; e + 4 <= wend; e += 4) {
    int2 m0 = bucketed[e + 0];
    int2 m1 = bucketed[e + 1];
    int2 m2 = bucketed[e + 2];
    int2 m3 = bucketed[e + 3];
    float g0 = h[(size_t)(m0.x & 0xFFFFF) * OUT_DIM + lane];
    float g1 = h[(size_t)(m1.x & 0xFFFFF) * OUT_DIM + lane];
    float g2 = h[(size_t)(m2.x & 0xFFFFF) * OUT_DIM + lane];
    float g3 = h[(size_t)(m3.x & 0xFFFFF) * OUT_DIM + lane];
    atomicAdd(&tile[((m0.x >> 20) & 63) * OUT_DIM + lane], __int_as_float(m0.y) * g0);
    atomicAdd(&tile[((m1.x >> 20) & 63) * OUT_DIM + lane], __int_as_float(m1.y) * g1);
    atomicAdd(&tile[((m2.x >> 20) & 63) * OUT_DIM + lane], __int_as_float(m2.y) * g2);
    atomicAdd(&tile[((m3.x >> 20) & 63) * OUT_DIM + lane], __int_as_float(m3.y) * g3);
  }
  for (; e < wend; ++e) {
    int2 m = bucketed[e];
    float g = h[(size_t)(m.x & 0xFFFFF) * OUT_DIM + lane];
    atomicAdd(&tile[((m.x >> 20) & 63) * OUT_DIM + lane], __int_as_float(m.y) * g);
  }
  __syncthreads();

  // writeout: 64 rows x 16 float4 = 1024 float4; wave covers 4 rows (1 KB)
  const float4* bias4 = reinterpret_cast<const float4*>(bias);
  for (int i = tid; i < BK_NODES * 16; i += 256) {
    int r = i >> 4, c4 = i & 15;
    int node = (b << BK_BITS) + r;
    if (node < nnodes) {
      float4 t = *reinterpret_cast<const float4*>(&tile[r * OUT_DIM + c4 * 4]);
      float4 bb = bias4[c4];
      float4 o = make_float4(t.x + bb.x, t.y + bb.y, t.z + bb.z, t.w + bb.w);
      *reinterpret_cast<float4*>(&out[(size_t)node * OUT_DIM + c4 * 4]) = o;
    }
  }
}

extern "C" void kernel_launch(void* const* d_in, const int* in_sizes, int n_in,
                              void* d_out, int out_size, void* d_ws, size_t ws_size,
                              hipStream_t stream) {
  const float* x    = (const float*)d_in[0];
  const int*   ei   = (const int*)d_in[1];    // [2, E]: row0 = dst, row1 = src
  const float* ew   = (const float*)d_in[2];
  const float* w    = (const float*)d_in[3];
  const float* bias = (const float*)d_in[4];
  float* out = (float*)d_out;

  const int nrows  = in_sizes[0] / IN_DIM;  // 100000
  const int nedges = in_sizes[2];           // 1600000
  const int nb     = (nrows + BK_NODES - 1) >> BK_BITS;  // 1563

  // ws layout
  char* ws = (char*)d_ws;
  size_t o = 0;
  float* h = (float*)(ws + o);            o += align_up((size_t)nrows * OUT_DIM * 4, 512);
  int* counts_pad = (int*)(ws + o);       o += align_up((size_t)nb * CPAD * 4, 512);
  int* cursor_pad = (int*)(ws + o);       o += align_up((size_t)nb * CPAD * 4, 512);
  int* offsets    = (int*)(ws + o);       o += align_up((size_t)(nb + 1) * 4, 512);
  int2* bucketed  = (int2*)(ws + o);      o += align_up((size_t)nedges * 8, 512);

  hipLaunchKernelGGL(gemm_block, dim3((nrows + 63) / 64), dim3(256), 0, stream,
                     x, w, h, nrows);
  hipLaunchKernelGGL(zero_i32, dim3(64), dim3(256), 0, stream,
                     counts_pad, nb * CPAD);
  hipLaunchKernelGGL(hist_lds_kernel, dim3(256), dim3(256), 0, stream,
                     ei, nedges, counts_pad, nb);
  hipLaunchKernelGGL(scan_buckets_kernel, dim3(1), dim3(1024), 0, stream,
                     counts_pad, nb, offsets, cursor_pad);
  hipLaunchKernelGGL(bucket_fill_kernel, dim3(2048), dim3(256), 0, stream,
                     ei, ew, nedges, cursor_pad, bucketed, nb);
  hipLaunchKernelGGL(lds_gather_kernel, dim3(nb), dim3(256), 0, stream,
                     offsets, bucketed, h, bias, out, nrows);
}

// Round 9
// 835.529 us; speedup vs baseline: 1.0027x; 1.0027x over previous
//
#include <hip/hip_runtime.h>

#define IN_DIM 128
#define OUT_DIM 64
#define PADF 36     // gemm LDS row stride in floats
#define BK_BITS 6   // 64-node buckets
#define BK_NODES 64
#define CPAD 16     // cursor/count padding: one int per 64B line

static inline size_t align_up(size_t v, size_t a) { return (v + a - 1) & ~(a - 1); }

// ---------- GEMM: h = x @ W ----------
// 256 threads = 4 waves; wave wv computes cols [16wv,16wv+16), lane = row.
// W loads wave-uniform -> s_load; acc[16] static -> VGPRs. (r6: left top-5)
__global__ __launch_bounds__(256, 8) void gemm_block(
    const float* __restrict__ x, const float* __restrict__ w,
    float* __restrict__ h, int nrows) {
  __shared__ float xt[64 * PADF];
  const int tid = threadIdx.x;
  const int lane = tid & 63;
  const int wv = __builtin_amdgcn_readfirstlane(tid >> 6);  // 0..3, SGPR
  const int rb = blockIdx.x * 64;

  float acc[16];
#pragma unroll
  for (int c = 0; c < 16; ++c) acc[c] = 0.f;

  const int r = tid >> 3;
  const int kq = (tid & 7) << 2;
  const float* wbase = w + wv * 16;

#pragma unroll 1
  for (int kc = 0; kc < IN_DIM; kc += 32) {
#pragma unroll
    for (int p = 0; p < 2; ++p) {
      int row = rb + r + p * 32;
      float4 v = (row < nrows)
                     ? *reinterpret_cast<const float4*>(x + (size_t)row * IN_DIM + kc + kq)
                     : make_float4(0.f, 0.f, 0.f, 0.f);
      *reinterpret_cast<float4*>(&xt[(r + p * 32) * PADF + kq]) = v;
    }
    __syncthreads();
#pragma unroll
    for (int k4 = 0; k4 < 32; k4 += 4) {
      float4 xv = *reinterpret_cast<const float4*>(&xt[lane * PADF + k4]);
#pragma unroll
      for (int kk = 0; kk < 4; ++kk) {
        float xs = (&xv.x)[kk];
        const float* wk = wbase + (size_t)(kc + k4 + kk) * OUT_DIM;  // uniform -> s_load
#pragma unroll
        for (int c = 0; c < 16; ++c)
          acc[c] = fmaf(xs, wk[c], acc[c]);
      }
    }
    __syncthreads();
  }

  int row = rb + lane;
  if (row < nrows) {
    float4* hp = reinterpret_cast<float4*>(h + (size_t)row * OUT_DIM + wv * 16);
#pragma unroll
    for (int c4 = 0; c4 < 4; ++c4)
      hp[c4] = make_float4(acc[c4 * 4], acc[c4 * 4 + 1], acc[c4 * 4 + 2], acc[c4 * 4 + 3]);
  }
}

// ---------- bucket CSR build ----------

__global__ __launch_bounds__(256) void zero_i32(int* __restrict__ p, int n) {
  int tid = blockIdx.x * blockDim.x + threadIdx.x;
  int stride = gridDim.x * blockDim.x;
  for (int i = tid; i < n; i += stride) p[i] = 0;
}

// Bucket histogram via per-block LDS (int LDS atomics are native ds_add_u32).
__global__ __launch_bounds__(256) void hist_lds_kernel(
    const int* __restrict__ dst, int nedges, int* __restrict__ counts_pad,
    int nb) {
  __shared__ int hcnt[2048];
  const int tid = threadIdx.x;
  for (int i = tid; i < nb; i += 256) hcnt[i] = 0;
  __syncthreads();
  int gid = blockIdx.x * blockDim.x + tid;
  int stride = gridDim.x * blockDim.x;
  for (int e = gid; e < nedges; e += stride) {
    int d = __builtin_nontemporal_load(dst + e);
    atomicAdd(&hcnt[d >> BK_BITS], 1);
  }
  __syncthreads();
  for (int i = tid; i < nb; i += 256) {
    int v = hcnt[i];
    if (v) atomicAdd(&counts_pad[i * CPAD], v);
  }
}

// Single-block exclusive scan of nb (<=2047) bucket counts.
__global__ __launch_bounds__(1024) void scan_buckets_kernel(
    const int* __restrict__ counts_pad, int nb, int* __restrict__ offsets,
    int* __restrict__ cursor_pad) {
  __shared__ int sb[2][2048];
  const int tid = threadIdx.x;
  const int i0 = tid * 2, i1 = tid * 2 + 1;
  sb[0][i0] = (i0 < nb) ? counts_pad[i0 * CPAD] : 0;
  sb[0][i1] = (i1 < nb) ? counts_pad[i1 * CPAD] : 0;
  __syncthreads();
  int cur = 0;
  for (int d = 1; d < 2048; d <<= 1) {
    int a0 = sb[cur][i0] + ((i0 >= d) ? sb[cur][i0 - d] : 0);
    int a1 = sb[cur][i1] + ((i1 >= d) ? sb[cur][i1 - d] : 0);
    sb[cur ^ 1][i0] = a0;
    sb[cur ^ 1][i1] = a1;
    cur ^= 1;
    __syncthreads();
  }
  if (i0 <= nb) {
    int e0 = (i0 == 0) ? 0 : sb[cur][i0 - 1];
    offsets[i0] = e0;
    if (i0 < nb) cursor_pad[i0 * CPAD] = e0;
  }
  if (i1 <= nb) {
    int e1 = sb[cur][i1 - 1];
    offsets[i1] = e1;
    if (i1 < nb) cursor_pad[i1 * CPAD] = e1;
  }
}

// XCD-range-partitioned bucket fill (r8: left the visible cost entirely).
__global__ __launch_bounds__(256) void bucket_fill_kernel(
    const int* __restrict__ ei, const float* __restrict__ ew, int nedges,
    int* __restrict__ cursor_pad, int2* __restrict__ bucketed, int nb) {
  const int range = blockIdx.x & 7;
  const int ngroups = gridDim.x >> 3;
  const int group = blockIdx.x >> 3;
  const int lo = (int)((size_t)range * nb / 8);
  const int hi = (int)((size_t)(range + 1) * nb / 8);
  int tid = group * blockDim.x + threadIdx.x;
  int stride = ngroups * blockDim.x;
  for (int e = tid; e < nedges; e += stride) {
    int d = __builtin_nontemporal_load(ei + e);
    int b = d >> BK_BITS;
    if (b >= lo && b < hi) {
      int s = ei[nedges + e];
      float wv = ew[e];
      int p = atomicAdd(&cursor_pad[b * CPAD], 1);
      bucketed[p] = make_int2(s | ((d & (BK_NODES - 1)) << 20),
                              __float_as_int(wv));
    }
  }
}

// ---------- LDS-gather: one block per bucket ----------
// r8 failure: atomicAdd(shared float) = CAS loop (safe-FP default) ->
// ~400 serialized cyc/edge, 595 us. Fix: unsafeAtomicAdd -> native
// ds_add_f32, fire-and-forget. ILP-8 keeps 8 h-row loads in flight.
__global__ __launch_bounds__(256) void lds_gather_kernel(
    const int* __restrict__ offsets, const int2* __restrict__ bucketed,
    const float* __restrict__ h, const float* __restrict__ bias,
    float* __restrict__ out, int nnodes) {
  __shared__ float tile[BK_NODES * OUT_DIM];  // 16 KB
  const int tid = threadIdx.x;
  const int lane = tid & 63;
  const int wv = __builtin_amdgcn_readfirstlane(tid >> 6);
  const int b = blockIdx.x;

#pragma unroll
  for (int i = 0; i < BK_NODES * OUT_DIM / 256; ++i)
    tile[tid + i * 256] = 0.f;
  __syncthreads();

  const int beg = offsets[b];
  const int end = offsets[b + 1];
  const int cnt = end - beg;
  const int per = (cnt + 3) >> 2;
  int e = beg + wv * per;
  const int wend = min(e + per, end);

  for (; e + 8 <= wend; e += 8) {
    int2 m[8];
#pragma unroll
    for (int i = 0; i < 8; ++i) m[i] = bucketed[e + i];
    float g[8];
#pragma unroll
    for (int i = 0; i < 8; ++i)
      g[i] = h[(size_t)(m[i].x & 0xFFFFF) * OUT_DIM + lane];
#pragma unroll
    for (int i = 0; i < 8; ++i)
      unsafeAtomicAdd(&tile[((m[i].x >> 20) & 63) * OUT_DIM + lane],
                      __int_as_float(m[i].y) * g[i]);
  }
  for (; e < wend; ++e) {
    int2 m = bucketed[e];
    float g = h[(size_t)(m.x & 0xFFFFF) * OUT_DIM + lane];
    unsafeAtomicAdd(&tile[((m.x >> 20) & 63) * OUT_DIM + lane],
                    __int_as_float(m.y) * g);
  }
  __syncthreads();

  // writeout: 64 rows x 16 float4; bias fused
  const float4* bias4 = reinterpret_cast<const float4*>(bias);
  for (int i = tid; i < BK_NODES * 16; i += 256) {
    int r = i >> 4, c4 = i & 15;
    int node = (b << BK_BITS) + r;
    if (node < nnodes) {
      float4 t = *reinterpret_cast<const float4*>(&tile[r * OUT_DIM + c4 * 4]);
      float4 bb = bias4[c4];
      float4 o = make_float4(t.x + bb.x, t.y + bb.y, t.z + bb.z, t.w + bb.w);
      *reinterpret_cast<float4*>(&out[(size_t)node * OUT_DIM + c4 * 4]) = o;
    }
  }
}

extern "C" void kernel_launch(void* const* d_in, const int* in_sizes, int n_in,
                              void* d_out, int out_size, void* d_ws, size_t ws_size,
                              hipStream_t stream) {
  const float* x    = (const float*)d_in[0];
  const int*   ei   = (const int*)d_in[1];    // [2, E]: row0 = dst, row1 = src
  const float* ew   = (const float*)d_in[2];
  const float* w    = (const float*)d_in[3];
  const float* bias = (const float*)d_in[4];
  float* out = (float*)d_out;

  const int nrows  = in_sizes[0] / IN_DIM;  // 100000
  const int nedges = in_sizes[2];           // 1600000
  const int nb     = (nrows + BK_NODES - 1) >> BK_BITS;  // 1563

  // ws layout
  char* ws = (char*)d_ws;
  size_t o = 0;
  float* h = (float*)(ws + o);            o += align_up((size_t)nrows * OUT_DIM * 4, 512);
  int* counts_pad = (int*)(ws + o);       o += align_up((size_t)nb * CPAD * 4, 512);
  int* cursor_pad = (int*)(ws + o);       o += align_up((size_t)nb * CPAD * 4, 512);
  int* offsets    = (int*)(ws + o);       o += align_up((size_t)(nb + 1) * 4, 512);
  int2* bucketed  = (int2*)(ws + o);      o += align_up((size_t)nedges * 8, 512);

  hipLaunchKernelGGL(gemm_block, dim3((nrows + 63) / 64), dim3(256), 0, stream,
                     x, w, h, nrows);
  hipLaunchKernelGGL(zero_i32, dim3(64), dim3(256), 0, stream,
                     counts_pad, nb * CPAD);
  hipLaunchKernelGGL(hist_lds_kernel, dim3(256), dim3(256), 0, stream,
                     ei, nedges, counts_pad, nb);
  hipLaunchKernelGGL(scan_buckets_kernel, dim3(1), dim3(1024), 0, stream,
                     counts_pad, nb, offsets, cursor_pad);
  hipLaunchKernelGGL(bucket_fill_kernel, dim3(2048), dim3(256), 0, stream,
                     ei, ew, nedges, cursor_pad, bucketed, nb);
  hipLaunchKernelGGL(lds_gather_kernel, dim3(nb), dim3(256), 0, stream,
                     offsets, bucketed, h, bias, out, nrows);
}